// Round 1
// baseline (3341.903 us; speedup 1.0000x reference)
//
#include <hip/hip_runtime.h>

// Problem constants
constexpr int Bsz = 2, Tsz = 512, Csz = 1024, Hsz = 16, Dsz = 64, CSz = 64;
constexpr int NCHUNK = 8, OW = 8;
constexpr int SP = 65;   // LDS row stride for 64x64 tiles (bank-conflict padding)

// Polar Express quintic coefficients (first NS_STEPS=5 rows)
__constant__ float PE_A[5] = {8.28721201814563f, 4.107059111542203f, 3.9486908534822946f,
                              3.3184196573706015f, 2.300652019954817f};
__constant__ float PE_B[5] = {-23.595886519098837f, -2.9478499167379106f, -2.908902115962949f,
                              -2.488488024314874f, -1.6689039845747493f};
__constant__ float PE_C[5] = {17.300387312530933f, 0.5448431082926601f, 0.5518191394370137f,
                              0.51004894012372f, 0.4188073119525673f};

// ---------------------------------------------------------------------------
// Generic tiled GEMM:  O[m][n] = sum_k A[m][k] * W[n][k]   (i.e. A @ W.T)
// BM=BN=64, BK=16, 256 threads, 4x4 micro-tile per thread.
// ---------------------------------------------------------------------------
__global__ __launch_bounds__(256) void gemm_nt(const float* __restrict__ A,
                                               const float* __restrict__ W,
                                               float* __restrict__ O,
                                               int M, int N, int K) {
  __shared__ float As[16][68];
  __shared__ float Ws[16][68];
  const int tid = threadIdx.x;
  const int m0 = blockIdx.x * 64, n0 = blockIdx.y * 64;
  const int tm = tid & 15, tn = tid >> 4;
  const int lr = tid >> 2, lk = (tid & 3) << 2;
  float acc[4][4] = {};
  for (int k0 = 0; k0 < K; k0 += 16) {
    float4 av = *(const float4*)(A + (size_t)(m0 + lr) * K + k0 + lk);
    float4 wv = *(const float4*)(W + (size_t)(n0 + lr) * K + k0 + lk);
    __syncthreads();
    As[lk + 0][lr] = av.x; As[lk + 1][lr] = av.y; As[lk + 2][lr] = av.z; As[lk + 3][lr] = av.w;
    Ws[lk + 0][lr] = wv.x; Ws[lk + 1][lr] = wv.y; Ws[lk + 2][lr] = wv.z; Ws[lk + 3][lr] = wv.w;
    __syncthreads();
#pragma unroll
    for (int k = 0; k < 16; ++k) {
      float4 a4 = *(const float4*)&As[k][tm << 2];
      float4 w4 = *(const float4*)&Ws[k][tn << 2];
      float a_[4] = {a4.x, a4.y, a4.z, a4.w};
      float w_[4] = {w4.x, w4.y, w4.z, w4.w};
#pragma unroll
      for (int i = 0; i < 4; ++i)
#pragma unroll
        for (int j = 0; j < 4; ++j) acc[i][j] += a_[i] * w_[j];
    }
  }
#pragma unroll
  for (int i = 0; i < 4; ++i) {
    float4 o = {acc[i][0], acc[i][1], acc[i][2], acc[i][3]};
    *(float4*)(O + (size_t)(m0 + (tm << 2) + i) * N + n0 + (tn << 2)) = o;
  }
}

// ---------------------------------------------------------------------------
// Gates: alpha/eta/theta/gamma[b,t,h] = sigmoid(x[b,t,:] . W*[h,:])
// One block per (b,t), 64 threads: tid -> (gate_sel = tid/16, h = tid%16)
// ---------------------------------------------------------------------------
__global__ __launch_bounds__(64) void gates_kernel(const float* __restrict__ x,
                                                   const float* __restrict__ Wa,
                                                   const float* __restrict__ We,
                                                   const float* __restrict__ Wt,
                                                   const float* __restrict__ Wg,
                                                   float* __restrict__ ga, float* __restrict__ ge,
                                                   float* __restrict__ gt, float* __restrict__ gg) {
  __shared__ float xs[Csz];
  const int bt = blockIdx.x;
  const int tid = threadIdx.x;
  const float* xr = x + (size_t)bt * Csz;
  for (int i = tid * 4; i < Csz; i += 64 * 4) *(float4*)&xs[i] = *(const float4*)&xr[i];
  __syncthreads();
  const int gsel = tid >> 4, h = tid & 15;
  const float* Wrow = (gsel == 0 ? Wa : gsel == 1 ? We : gsel == 2 ? Wt : Wg) + (size_t)h * Csz;
  float acc = 0.f;
  for (int i = 0; i < Csz; i += 4) {
    float4 w4 = *(const float4*)&Wrow[i];
    acc += xs[i] * w4.x + xs[i + 1] * w4.y + xs[i + 2] * w4.z + xs[i + 3] * w4.w;
  }
  float s = 1.f / (1.f + expf(-acc));
  float* outp = (gsel == 0 ? ga : gsel == 1 ? ge : gsel == 2 ? gt : gg);
  outp[(size_t)bt * Hsz + h] = s;
}

// ---------------------------------------------------------------------------
// Causal depthwise conv (K=4) + optional (rms_norm over head dim + poly).
// One block per (b,t), 256 threads x 4 channels. Head = 64 channels = 16 lanes.
// ---------------------------------------------------------------------------
__global__ __launch_bounds__(256) void conv_kernel(const float* __restrict__ lin,
                                                   const float* __restrict__ w,
                                                   const float* __restrict__ bias,
                                                   float* __restrict__ out, int do_norm) {
  const int bt = blockIdx.x;
  const int b = bt >> 9, t = bt & 511;  // T = 512
  const int tid = threadIdx.x;
  const int c0 = tid << 2;
  float4 bv = *(const float4*)&bias[c0];
  float v0 = bv.x, v1 = bv.y, v2 = bv.z, v3 = bv.w;
  float4 w0 = *(const float4*)&w[(c0 + 0) * 4];
  float4 w1 = *(const float4*)&w[(c0 + 1) * 4];
  float4 w2 = *(const float4*)&w[(c0 + 2) * 4];
  float4 w3 = *(const float4*)&w[(c0 + 3) * 4];
  const float* base = lin + (size_t)b * Tsz * Csz + c0;
#pragma unroll
  for (int j = 0; j < 4; ++j) {
    int tt = t - 3 + j;
    if (tt < 0) continue;
    float4 xv = *(const float4*)(base + (size_t)tt * Csz);
    v0 += xv.x * (&w0.x)[j];
    v1 += xv.y * (&w1.x)[j];
    v2 += xv.z * (&w2.x)[j];
    v3 += xv.w * (&w3.x)[j];
  }
  if (do_norm) {
    float ss = v0 * v0 + v1 * v1 + v2 * v2 + v3 * v3;
    ss += __shfl_xor(ss, 1, 16);
    ss += __shfl_xor(ss, 2, 16);
    ss += __shfl_xor(ss, 4, 16);
    ss += __shfl_xor(ss, 8, 16);
    float scl = rsqrtf(ss * (1.f / 64.f) + 1e-6f);
    v0 *= scl; v1 *= scl; v2 *= scl; v3 *= scl;
    v0 += 0.5f * v0 * v0; v1 += 0.5f * v1 * v1; v2 += 0.5f * v2 * v2; v3 += 0.5f * v3 * v3;
  }
  float4 o = {v0, v1, v2, v3};
  *(float4*)(out + (size_t)bt * Csz + c0) = o;
}

// ---------------------------------------------------------------------------
// rms_norm over head dim for the y buffer
// ---------------------------------------------------------------------------
__global__ __launch_bounds__(256) void rms_kernel(const float* __restrict__ in,
                                                  float* __restrict__ out) {
  const int bt = blockIdx.x;
  const int tid = threadIdx.x;
  const int c0 = tid << 2;
  float4 xv = *(const float4*)(in + (size_t)bt * Csz + c0);
  float ss = xv.x * xv.x + xv.y * xv.y + xv.z * xv.z + xv.w * xv.w;
  ss += __shfl_xor(ss, 1, 16);
  ss += __shfl_xor(ss, 2, 16);
  ss += __shfl_xor(ss, 4, 16);
  ss += __shfl_xor(ss, 8, 16);
  float scl = rsqrtf(ss * (1.f / 64.f) + 1e-6f);
  float4 o = {xv.x * scl, xv.y * scl, xv.z * scl, xv.w * scl};
  *(float4*)(out + (size_t)bt * Csz + c0) = o;
}

// ---------------------------------------------------------------------------
// B1: err[bh][t][v] = (sum_k M[bh][v][k] * k_c[t][k]) - v_c[t][v]
// One block per (b,h). Wave w handles 16 t-rows, lane = v.
// ---------------------------------------------------------------------------
__global__ __launch_bounds__(256) void pred_err_kernel(const float* __restrict__ Mst,
                                                       const float* __restrict__ kp,
                                                       const float* __restrict__ vp,
                                                       float* __restrict__ errb, int ci) {
  __shared__ float Ml[Dsz][SP];
  __shared__ float kl[CSz][Dsz];
  const int bh = blockIdx.x;
  const int b = bh >> 4, h = bh & 15;
  const int tid = threadIdx.x;
  const float* Mp = Mst + (size_t)bh * Dsz * Dsz;
  for (int i = tid; i < Dsz * Dsz; i += 256) Ml[i >> 6][i & 63] = Mp[i];
  for (int i = tid; i < CSz * Dsz; i += 256) {
    int t = i >> 6, k = i & 63;
    kl[t][k] = kp[(((size_t)b * Tsz + ci * CSz + t) * Hsz + h) * Dsz + k];
  }
  __syncthreads();
  const int w = tid >> 6, lane = tid & 63;
  for (int ti = 0; ti < 16; ++ti) {
    int t = w * 16 + ti;
    float acc = 0.f;
#pragma unroll 4
    for (int k = 0; k < Dsz; ++k) acc += kl[t][k] * Ml[lane][k];
    float vv = vp[(((size_t)b * Tsz + ci * CSz + t) * Hsz + h) * Dsz + lane];
    errb[((size_t)bh * CSz + t) * Dsz + lane] = acc - vv;
  }
}

// ---------------------------------------------------------------------------
// B2: u = 2*err⊗k, omega window (W=8) with gamma, mom_in = -eta*u~,
//     momentum scan S_t = theta_t*S_{t-1} + mom_in_t. Thread per (v,k) element.
// Grid: (B*H)*16 blocks; block handles 4 v-rows (eb), all 64 k.
// ---------------------------------------------------------------------------
__global__ __launch_bounds__(256) void mom_scan_kernel(const float* __restrict__ errb,
                                                       const float* __restrict__ kp,
                                                       const float* __restrict__ geta,
                                                       const float* __restrict__ gtheta,
                                                       const float* __restrict__ ggamma,
                                                       float* __restrict__ Sst,
                                                       float* __restrict__ chunkS, int ci) {
  __shared__ float errl[256];       // [t][vloc]  (4 v-rows of this block)
  __shared__ float kkl[CSz * Dsz];  // [t][k]
  __shared__ float gl[CSz], el[CSz], tl[CSz];
  const int blk = blockIdx.x;
  const int bh = blk >> 4, eb = blk & 15;
  const int b = bh >> 4, h = bh & 15;
  const int tid = threadIdx.x;
  errl[tid] = errb[((size_t)bh * CSz + (tid >> 2)) * Dsz + eb * 4 + (tid & 3)];
#pragma unroll
  for (int i = 0; i < 16; ++i) {
    int idx = i * 256 + tid;
    int t = idx >> 6, k = idx & 63;
    kkl[idx] = kp[(((size_t)b * Tsz + ci * CSz + t) * Hsz + h) * Dsz + k];
  }
  if (tid < CSz) {
    size_t gi = ((size_t)b * Tsz + ci * CSz + tid) * Hsz + h;
    gl[tid] = ggamma[gi];
    el[tid] = geta[gi];
    tl[tid] = gtheta[gi];
  }
  __syncthreads();
  const int e = eb * 256 + tid;       // global (v,k) element id
  const int vloc = tid >> 6;          // wave-uniform
  const int k = tid & 63;
  float S = Sst[(size_t)bh * 4096 + e];
  float ring[OW];
  float wsum = 0.f;
  float* outp = chunkS + (size_t)bh * CSz * 4096 + e;
#pragma unroll
  for (int t = 0; t < CSz; ++t) {
    float u = 2.f * errl[t * 4 + vloc] * kkl[t * 64 + k];
    float val = gl[t] * u;
    wsum += val;
    if (t >= OW) wsum -= ring[t & (OW - 1)];
    ring[t & (OW - 1)] = val;
    S = tl[t] * S - el[t] * wsum;
    outp[(size_t)t * 4096] = S;
  }
  Sst[(size_t)bh * 4096 + e] = S;
}

// ---------------------------------------------------------------------------
// B3: Polar Express orthogonalization, in-place on each 64x64 matrix.
// One 256-thread block per matrix; 3 LDS buffers with stride-65 padding.
// ---------------------------------------------------------------------------
__device__ __forceinline__ void mm_xxt(const float* X, float* O, int r, int c) {
  // O = X @ X^T
  float acc[4][4] = {};
#pragma unroll 4
  for (int k = 0; k < 64; ++k) {
    float p[4], q[4];
#pragma unroll
    for (int i = 0; i < 4; ++i) p[i] = X[(4 * r + i) * SP + k];
#pragma unroll
    for (int j = 0; j < 4; ++j) q[j] = X[(4 * c + j) * SP + k];
#pragma unroll
    for (int i = 0; i < 4; ++i)
#pragma unroll
      for (int j = 0; j < 4; ++j) acc[i][j] += p[i] * q[j];
  }
#pragma unroll
  for (int i = 0; i < 4; ++i)
#pragma unroll
    for (int j = 0; j < 4; ++j) O[(4 * r + i) * SP + 4 * c + j] = acc[i][j];
}

__device__ __forceinline__ void mm_nn(const float* P, const float* Q, float* O, int r, int c) {
  // O = P @ Q
  float acc[4][4] = {};
#pragma unroll 4
  for (int k = 0; k < 64; ++k) {
    float p[4], q[4];
#pragma unroll
    for (int i = 0; i < 4; ++i) p[i] = P[(4 * r + i) * SP + k];
#pragma unroll
    for (int j = 0; j < 4; ++j) q[j] = Q[k * SP + 4 * c + j];
#pragma unroll
    for (int i = 0; i < 4; ++i)
#pragma unroll
      for (int j = 0; j < 4; ++j) acc[i][j] += p[i] * q[j];
  }
#pragma unroll
  for (int i = 0; i < 4; ++i)
#pragma unroll
    for (int j = 0; j < 4; ++j) O[(4 * r + i) * SP + 4 * c + j] = acc[i][j];
}

__device__ __forceinline__ void mm_axpy(const float* Bm, const float* X, float* O, float a,
                                        int r, int c) {
  // O = a*X + Bm @ X
  float acc[4][4] = {};
#pragma unroll 4
  for (int k = 0; k < 64; ++k) {
    float p[4], q[4];
#pragma unroll
    for (int i = 0; i < 4; ++i) p[i] = Bm[(4 * r + i) * SP + k];
#pragma unroll
    for (int j = 0; j < 4; ++j) q[j] = X[k * SP + 4 * c + j];
#pragma unroll
    for (int i = 0; i < 4; ++i)
#pragma unroll
      for (int j = 0; j < 4; ++j) acc[i][j] += p[i] * q[j];
  }
#pragma unroll
  for (int i = 0; i < 4; ++i)
#pragma unroll
    for (int j = 0; j < 4; ++j)
      O[(4 * r + i) * SP + 4 * c + j] = a * X[(4 * r + i) * SP + 4 * c + j] + acc[i][j];
}

__global__ __launch_bounds__(256) void pe_kernel(float* __restrict__ chunkS) {
  __shared__ float buf0[64 * SP], buf1[64 * SP], buf2[64 * SP];
  __shared__ float red[4];
  const int tid = threadIdx.x;
  float* G = chunkS + (size_t)blockIdx.x * 4096;
  float vals[16];
  float ss = 0.f;
#pragma unroll
  for (int i = 0; i < 16; ++i) {
    float xv = G[i * 256 + tid];
    vals[i] = xv;
    ss += xv * xv;
  }
#pragma unroll
  for (int off = 32; off; off >>= 1) ss += __shfl_xor(ss, off, 64);
  if ((tid & 63) == 0) red[tid >> 6] = ss;
  __syncthreads();
  float tot = red[0] + red[1] + red[2] + red[3];
  float scale = 1.f / ((sqrtf(tot) + 1e-7f) * 1.01f);
#pragma unroll
  for (int i = 0; i < 16; ++i) {
    int idx = i * 256 + tid;
    buf0[(idx >> 6) * SP + (idx & 63)] = vals[i] * scale;
  }
  float* pX = buf0;
  float* pA = buf1;
  float* pB = buf2;
  const int r = tid >> 4, c = tid & 15;
  for (int it = 0; it < 5; ++it) {
    const float a = PE_A[it], bco = PE_B[it], cco = PE_C[it];
    __syncthreads();
    mm_xxt(pX, pA, r, c);        // A = X X^T
    __syncthreads();
    mm_nn(pA, pA, pB, r, c);     // A2 = A A
    __syncthreads();
#pragma unroll
    for (int i = 0; i < 16; ++i) {
      int idx = i * 256 + tid;
      int o = (idx >> 6) * SP + (idx & 63);
      pA[o] = bco * pA[o] + cco * pB[o];   // Bmat = b*A + c*A2
    }
    __syncthreads();
    mm_axpy(pA, pX, pB, a, r, c);          // X' = a*X + Bmat X
    float* tmp = pX; pX = pB; pB = tmp;
  }
  __syncthreads();
#pragma unroll
  for (int i = 0; i < 16; ++i) {
    int idx = i * 256 + tid;
    G[idx] = pX[(idx >> 6) * SP + (idx & 63)];
  }
}

// ---------------------------------------------------------------------------
// B4: memory scan M_t = alpha_t*M_{t-1} + Xorth_t  and  y_t = M_t q_t.
// Grid (B*H)*16; wave w of block eb owns v = eb*4+w, lane = k.
// ---------------------------------------------------------------------------
__global__ __launch_bounds__(256) void mem_scan_kernel(const float* __restrict__ chunkS,
                                                       const float* __restrict__ qp,
                                                       const float* __restrict__ galpha,
                                                       float* __restrict__ Mst,
                                                       float* __restrict__ ybuf, int ci) {
  __shared__ float ql[CSz * Dsz];
  __shared__ float al[CSz];
  const int blk = blockIdx.x;
  const int bh = blk >> 4, eb = blk & 15;
  const int b = bh >> 4, h = bh & 15;
  const int tid = threadIdx.x;
  const int w = tid >> 6, lane = tid & 63;
  const int v = eb * 4 + w, k = lane;
  for (int i = tid; i < CSz * Dsz; i += 256) {
    int t = i >> 6, kk = i & 63;
    ql[i] = qp[(((size_t)b * Tsz + ci * CSz + t) * Hsz + h) * Dsz + kk];
  }
  if (tid < CSz) al[tid] = galpha[((size_t)b * Tsz + ci * CSz + tid) * Hsz + h];
  __syncthreads();
  float m = Mst[(size_t)bh * 4096 + v * 64 + k];
  const float* Xo = chunkS + (size_t)bh * CSz * 4096;
  for (int t = 0; t < CSz; ++t) {
    m = al[t] * m + Xo[(size_t)t * 4096 + v * 64 + k];
    float p = m * ql[t * 64 + k];
#pragma unroll
    for (int off = 32; off; off >>= 1) p += __shfl_xor(p, off, 64);
    if (lane == 0) ybuf[(((size_t)b * Tsz + ci * CSz + t) * Hsz + h) * Dsz + v] = p;
  }
  Mst[(size_t)bh * 4096 + v * 64 + k] = m;
}

// ---------------------------------------------------------------------------
extern "C" void kernel_launch(void* const* d_in, const int* in_sizes, int n_in,
                              void* d_out, int out_size, void* d_ws, size_t ws_size,
                              hipStream_t stream) {
  (void)in_sizes; (void)n_in; (void)out_size; (void)ws_size;
  const float* x   = (const float*)d_in[0];
  const float* Wq  = (const float*)d_in[1];
  const float* Wk  = (const float*)d_in[2];
  const float* Wv  = (const float*)d_in[3];
  const float* Wo  = (const float*)d_in[4];
  const float* cqw = (const float*)d_in[5];
  const float* cqb = (const float*)d_in[6];
  const float* ckw = (const float*)d_in[7];
  const float* ckb = (const float*)d_in[8];
  const float* cvw = (const float*)d_in[9];
  const float* cvb = (const float*)d_in[10];
  const float* Wa  = (const float*)d_in[11];
  const float* We  = (const float*)d_in[12];
  const float* Wt  = (const float*)d_in[13];
  const float* Wg  = (const float*)d_in[14];
  float* out = (float*)d_out;

  float* p = (float*)d_ws;
  const size_t NBTC = (size_t)Bsz * Tsz * Csz;     // 1048576
  const size_t NBTH = (size_t)Bsz * Tsz * Hsz;     // 16384
  const size_t NMAT = (size_t)Bsz * Hsz * Dsz * Dsz; // 131072
  float* qlin = p; p += NBTC;
  float* klin = p; p += NBTC;
  float* vlin = p; p += NBTC;
  float* qp   = p; p += NBTC;
  float* kp   = p; p += NBTC;
  float* vp   = p; p += NBTC;
  float* ga   = p; p += NBTH;
  float* ge   = p; p += NBTH;
  float* gt   = p; p += NBTH;
  float* gg   = p; p += NBTH;
  float* Mst  = p; p += NMAT;
  float* Sst  = p; p += NMAT;
  float* errb = p; p += (size_t)Bsz * Hsz * CSz * Dsz;           // 131072
  float* chS  = p; p += (size_t)Bsz * Hsz * CSz * Dsz * Dsz;     // 8388608
  float* ybuf = p; p += NBTC;
  float* ynrm = p; p += NBTC;

  hipMemsetAsync(Mst, 0, NMAT * sizeof(float), stream);
  hipMemsetAsync(Sst, 0, NMAT * sizeof(float), stream);

  dim3 gg16(16, 16);
  gemm_nt<<<gg16, 256, 0, stream>>>(x, Wq, qlin, Bsz * Tsz, Csz, Csz);
  gemm_nt<<<gg16, 256, 0, stream>>>(x, Wk, klin, Bsz * Tsz, Csz, Csz);
  gemm_nt<<<gg16, 256, 0, stream>>>(x, Wv, vlin, Bsz * Tsz, Csz, Csz);
  gates_kernel<<<Bsz * Tsz, 64, 0, stream>>>(x, Wa, We, Wt, Wg, ga, ge, gt, gg);
  conv_kernel<<<Bsz * Tsz, 256, 0, stream>>>(qlin, cqw, cqb, qp, 1);
  conv_kernel<<<Bsz * Tsz, 256, 0, stream>>>(klin, ckw, ckb, kp, 1);
  conv_kernel<<<Bsz * Tsz, 256, 0, stream>>>(vlin, cvw, cvb, vp, 0);

  for (int ci = 0; ci < NCHUNK; ++ci) {
    pred_err_kernel<<<Bsz * Hsz, 256, 0, stream>>>(Mst, kp, vp, errb, ci);
    mom_scan_kernel<<<Bsz * Hsz * 16, 256, 0, stream>>>(errb, kp, ge, gt, gg, Sst, chS, ci);
    pe_kernel<<<Bsz * Hsz * CSz, 256, 0, stream>>>(chS);
    mem_scan_kernel<<<Bsz * Hsz * 16, 256, 0, stream>>>(chS, qp, ga, Mst, ybuf, ci);
  }

  rms_kernel<<<Bsz * Tsz, 256, 0, stream>>>(ybuf, ynrm);
  gemm_nt<<<gg16, 256, 0, stream>>>(ynrm, Wo, out, Bsz * Tsz, Csz, Csz);
}

// Round 3
// 1483.464 us; speedup vs baseline: 2.2528x; 2.2528x over previous
//
#include <hip/hip_runtime.h>

// Problem constants
constexpr int Bsz = 2, Tsz = 512, Csz = 1024, Hsz = 16, Dsz = 64, CSz = 64;
constexpr int NCHUNK = 8, OW = 8;
constexpr int SP = 65;    // LDS row stride for fp32 64x64 tiles (legacy kernels)
constexpr int BP = 72;    // LDS row pitch (f16) : multiple of 8 keeps b128 16B-aligned

// Polar Express quintic coefficients (first NS_STEPS=5 rows)
__constant__ float PE_A[5] = {8.28721201814563f, 4.107059111542203f, 3.9486908534822946f,
                              3.3184196573706015f, 2.300652019954817f};
__constant__ float PE_B[5] = {-23.595886519098837f, -2.9478499167379106f, -2.908902115962949f,
                              -2.488488024314874f, -1.6689039845747493f};
__constant__ float PE_C[5] = {17.300387312530933f, 0.5448431082926601f, 0.5518191394370137f,
                              0.51004894012372f, 0.4188073119525673f};

typedef __attribute__((ext_vector_type(8))) _Float16 half8;
typedef __attribute__((ext_vector_type(16))) float f32x16;

// ---------------------------------------------------------------------------
// Generic tiled GEMM:  O[m][n] = sum_k A[m][k] * W[n][k]   (i.e. A @ W.T)
// ---------------------------------------------------------------------------
__global__ __launch_bounds__(256) void gemm_nt(const float* __restrict__ A,
                                               const float* __restrict__ W,
                                               float* __restrict__ O,
                                               int M, int N, int K) {
  __shared__ float As[16][68];
  __shared__ float Ws[16][68];
  const int tid = threadIdx.x;
  const int m0 = blockIdx.x * 64, n0 = blockIdx.y * 64;
  const int tm = tid & 15, tn = tid >> 4;
  const int lr = tid >> 2, lk = (tid & 3) << 2;
  float acc[4][4] = {};
  for (int k0 = 0; k0 < K; k0 += 16) {
    float4 av = *(const float4*)(A + (size_t)(m0 + lr) * K + k0 + lk);
    float4 wv = *(const float4*)(W + (size_t)(n0 + lr) * K + k0 + lk);
    __syncthreads();
    As[lk + 0][lr] = av.x; As[lk + 1][lr] = av.y; As[lk + 2][lr] = av.z; As[lk + 3][lr] = av.w;
    Ws[lk + 0][lr] = wv.x; Ws[lk + 1][lr] = wv.y; Ws[lk + 2][lr] = wv.z; Ws[lk + 3][lr] = wv.w;
    __syncthreads();
#pragma unroll
    for (int k = 0; k < 16; ++k) {
      float4 a4 = *(const float4*)&As[k][tm << 2];
      float4 w4 = *(const float4*)&Ws[k][tn << 2];
      float a_[4] = {a4.x, a4.y, a4.z, a4.w};
      float w_[4] = {w4.x, w4.y, w4.z, w4.w};
#pragma unroll
      for (int i = 0; i < 4; ++i)
#pragma unroll
        for (int j = 0; j < 4; ++j) acc[i][j] += a_[i] * w_[j];
    }
  }
#pragma unroll
  for (int i = 0; i < 4; ++i) {
    float4 o = {acc[i][0], acc[i][1], acc[i][2], acc[i][3]};
    *(float4*)(O + (size_t)(m0 + (tm << 2) + i) * N + n0 + (tn << 2)) = o;
  }
}

// ---------------------------------------------------------------------------
// Gates
// ---------------------------------------------------------------------------
__global__ __launch_bounds__(64) void gates_kernel(const float* __restrict__ x,
                                                   const float* __restrict__ Wa,
                                                   const float* __restrict__ We,
                                                   const float* __restrict__ Wt,
                                                   const float* __restrict__ Wg,
                                                   float* __restrict__ ga, float* __restrict__ ge,
                                                   float* __restrict__ gt, float* __restrict__ gg) {
  __shared__ float xs[Csz];
  const int bt = blockIdx.x;
  const int tid = threadIdx.x;
  const float* xr = x + (size_t)bt * Csz;
  for (int i = tid * 4; i < Csz; i += 64 * 4) *(float4*)&xs[i] = *(const float4*)&xr[i];
  __syncthreads();
  const int gsel = tid >> 4, h = tid & 15;
  const float* Wrow = (gsel == 0 ? Wa : gsel == 1 ? We : gsel == 2 ? Wt : Wg) + (size_t)h * Csz;
  float acc = 0.f;
  for (int i = 0; i < Csz; i += 4) {
    float4 w4 = *(const float4*)&Wrow[i];
    acc += xs[i] * w4.x + xs[i + 1] * w4.y + xs[i + 2] * w4.z + xs[i + 3] * w4.w;
  }
  float s = 1.f / (1.f + expf(-acc));
  float* outp = (gsel == 0 ? ga : gsel == 1 ? ge : gsel == 2 ? gt : gg);
  outp[(size_t)bt * Hsz + h] = s;
}

// ---------------------------------------------------------------------------
// Causal depthwise conv (K=4) + optional rms_norm/poly
// ---------------------------------------------------------------------------
__global__ __launch_bounds__(256) void conv_kernel(const float* __restrict__ lin,
                                                   const float* __restrict__ w,
                                                   const float* __restrict__ bias,
                                                   float* __restrict__ out, int do_norm) {
  const int bt = blockIdx.x;
  const int b = bt >> 9, t = bt & 511;
  const int tid = threadIdx.x;
  const int c0 = tid << 2;
  float4 bv = *(const float4*)&bias[c0];
  float v0 = bv.x, v1 = bv.y, v2 = bv.z, v3 = bv.w;
  float4 w0 = *(const float4*)&w[(c0 + 0) * 4];
  float4 w1 = *(const float4*)&w[(c0 + 1) * 4];
  float4 w2 = *(const float4*)&w[(c0 + 2) * 4];
  float4 w3 = *(const float4*)&w[(c0 + 3) * 4];
  const float* base = lin + (size_t)b * Tsz * Csz + c0;
#pragma unroll
  for (int j = 0; j < 4; ++j) {
    int tt = t - 3 + j;
    if (tt < 0) continue;
    float4 xv = *(const float4*)(base + (size_t)tt * Csz);
    v0 += xv.x * (&w0.x)[j];
    v1 += xv.y * (&w1.x)[j];
    v2 += xv.z * (&w2.x)[j];
    v3 += xv.w * (&w3.x)[j];
  }
  if (do_norm) {
    float ss = v0 * v0 + v1 * v1 + v2 * v2 + v3 * v3;
    ss += __shfl_xor(ss, 1, 16);
    ss += __shfl_xor(ss, 2, 16);
    ss += __shfl_xor(ss, 4, 16);
    ss += __shfl_xor(ss, 8, 16);
    float scl = rsqrtf(ss * (1.f / 64.f) + 1e-6f);
    v0 *= scl; v1 *= scl; v2 *= scl; v3 *= scl;
    v0 += 0.5f * v0 * v0; v1 += 0.5f * v1 * v1; v2 += 0.5f * v2 * v2; v3 += 0.5f * v3 * v3;
  }
  float4 o = {v0, v1, v2, v3};
  *(float4*)(out + (size_t)bt * Csz + c0) = o;
}

// ---------------------------------------------------------------------------
// rms_norm for y
// ---------------------------------------------------------------------------
__global__ __launch_bounds__(256) void rms_kernel(const float* __restrict__ in,
                                                  float* __restrict__ out) {
  const int bt = blockIdx.x;
  const int tid = threadIdx.x;
  const int c0 = tid << 2;
  float4 xv = *(const float4*)(in + (size_t)bt * Csz + c0);
  float ss = xv.x * xv.x + xv.y * xv.y + xv.z * xv.z + xv.w * xv.w;
  ss += __shfl_xor(ss, 1, 16);
  ss += __shfl_xor(ss, 2, 16);
  ss += __shfl_xor(ss, 4, 16);
  ss += __shfl_xor(ss, 8, 16);
  float scl = rsqrtf(ss * (1.f / 64.f) + 1e-6f);
  float4 o = {xv.x * scl, xv.y * scl, xv.z * scl, xv.w * scl};
  *(float4*)(out + (size_t)bt * Csz + c0) = o;
}

// ---------------------------------------------------------------------------
// B1: err = M k - v
// ---------------------------------------------------------------------------
__global__ __launch_bounds__(256) void pred_err_kernel(const float* __restrict__ Mst,
                                                       const float* __restrict__ kp,
                                                       const float* __restrict__ vp,
                                                       float* __restrict__ errb, int ci) {
  __shared__ float Ml[Dsz][SP];
  __shared__ float kl[CSz][Dsz];
  const int bh = blockIdx.x;
  const int b = bh >> 4, h = bh & 15;
  const int tid = threadIdx.x;
  const float* Mp = Mst + (size_t)bh * Dsz * Dsz;
  for (int i = tid; i < Dsz * Dsz; i += 256) Ml[i >> 6][i & 63] = Mp[i];
  for (int i = tid; i < CSz * Dsz; i += 256) {
    int t = i >> 6, k = i & 63;
    kl[t][k] = kp[(((size_t)b * Tsz + ci * CSz + t) * Hsz + h) * Dsz + k];
  }
  __syncthreads();
  const int w = tid >> 6, lane = tid & 63;
  for (int ti = 0; ti < 16; ++ti) {
    int t = w * 16 + ti;
    float acc = 0.f;
#pragma unroll 4
    for (int k = 0; k < Dsz; ++k) acc += kl[t][k] * Ml[lane][k];
    float vv = vp[(((size_t)b * Tsz + ci * CSz + t) * Hsz + h) * Dsz + lane];
    errb[((size_t)bh * CSz + t) * Dsz + lane] = acc - vv;
  }
}

// ---------------------------------------------------------------------------
// B2: omega window + momentum scan
// ---------------------------------------------------------------------------
__global__ __launch_bounds__(256) void mom_scan_kernel(const float* __restrict__ errb,
                                                       const float* __restrict__ kp,
                                                       const float* __restrict__ geta,
                                                       const float* __restrict__ gtheta,
                                                       const float* __restrict__ ggamma,
                                                       float* __restrict__ Sst,
                                                       float* __restrict__ chunkS, int ci) {
  __shared__ float errl[256];
  __shared__ float kkl[CSz * Dsz];
  __shared__ float gl[CSz], el[CSz], tl[CSz];
  const int blk = blockIdx.x;
  const int bh = blk >> 4, eb = blk & 15;
  const int b = bh >> 4, h = bh & 15;
  const int tid = threadIdx.x;
  errl[tid] = errb[((size_t)bh * CSz + (tid >> 2)) * Dsz + eb * 4 + (tid & 3)];
#pragma unroll
  for (int i = 0; i < 16; ++i) {
    int idx = i * 256 + tid;
    int t = idx >> 6, k = idx & 63;
    kkl[idx] = kp[(((size_t)b * Tsz + ci * CSz + t) * Hsz + h) * Dsz + k];
  }
  if (tid < CSz) {
    size_t gi = ((size_t)b * Tsz + ci * CSz + tid) * Hsz + h;
    gl[tid] = ggamma[gi];
    el[tid] = geta[gi];
    tl[tid] = gtheta[gi];
  }
  __syncthreads();
  const int e = eb * 256 + tid;
  const int vloc = tid >> 6;
  const int k = tid & 63;
  float S = Sst[(size_t)bh * 4096 + e];
  float ring[OW];
  float wsum = 0.f;
  float* outp = chunkS + (size_t)bh * CSz * 4096 + e;
#pragma unroll
  for (int t = 0; t < CSz; ++t) {
    float u = 2.f * errl[t * 4 + vloc] * kkl[t * 64 + k];
    float val = gl[t] * u;
    wsum += val;
    if (t >= OW) wsum -= ring[t & (OW - 1)];
    ring[t & (OW - 1)] = val;
    S = tl[t] * S - el[t] * wsum;
    outp[(size_t)t * 4096] = S;
  }
  Sst[(size_t)bh * 4096 + e] = S;
}

// ---------------------------------------------------------------------------
// B3: Polar Express via scaled split-f16 MFMA.
// One 256-thread block (4 waves) per 64x64 matrix; each wave owns one 32x32
// output tile. All MFMA operands are contiguous LDS row reads:
//   A  = X X^T        : A-op rows of X, B-op rows of X (B = X^T)
//   A2 = A A          : A symmetric -> B-op rows of A
//   X' = (aI+bA+cA2) X: A-op rows of Bm' (symmetric), B-op rows of XT
// fp32 v ~= hi + (lo/2048), hi/lo f16 RN; lo stored pre-scaled by 2048 so it
// stays in the f16 normal range. Products: hh -> accH, h*lo + lo*h -> accL;
// result = accH + accL/2048  (~2^-22 relative, ~fp32-grade for this use).
// ---------------------------------------------------------------------------
__device__ __forceinline__ void split_f16(float v, _Float16& hi, _Float16& lo) {
  _Float16 h = (_Float16)v;                 // RN
  float r = v - (float)h;                   // exact residual
  hi = h;
  lo = (_Float16)(r * 2048.0f);             // RN, scaled into normal range
}

__device__ __forceinline__ half8 ldfrag(const _Float16* P, int rowbase, int ks, int lane) {
  // fragment for v_mfma_f32_32x32x16_f16: lane -> m/n = lane&31, k = 8*(lane>>5)+j
  int row = rowbase + (lane & 31);
  int col = (ks << 4) + ((lane >> 5) << 3);
  return *(const half8*)&P[row * BP + col];
}

#define MFMA2(accH, accL, ah, al, bh, bl)                                     \
  accH = __builtin_amdgcn_mfma_f32_32x32x16_f16(ah, bh, accH, 0, 0, 0);       \
  accL = __builtin_amdgcn_mfma_f32_32x32x16_f16(ah, bl, accL, 0, 0, 0);       \
  accL = __builtin_amdgcn_mfma_f32_32x32x16_f16(al, bh, accL, 0, 0, 0);

__global__ __launch_bounds__(256) void pe_mfma_kernel(float* __restrict__ chunkS) {
  __shared__ __attribute__((aligned(16))) _Float16 Xhi[64 * BP];
  __shared__ __attribute__((aligned(16))) _Float16 Xlo[64 * BP];
  __shared__ __attribute__((aligned(16))) _Float16 XThi[64 * BP];
  __shared__ __attribute__((aligned(16))) _Float16 XTlo[64 * BP];
  __shared__ __attribute__((aligned(16))) _Float16 Ahi[64 * BP];
  __shared__ __attribute__((aligned(16))) _Float16 Alo[64 * BP];
  __shared__ float red[4];
  const int tid = threadIdx.x;
  const int lane = tid & 63;
  const int wv = tid >> 6;
  float* G = chunkS + (size_t)blockIdx.x * 4096;
  constexpr float INV_S = 1.0f / 2048.0f;

  // ---- load + Frobenius normalize ----
  float vals[16];
  float ss = 0.f;
#pragma unroll
  for (int i = 0; i < 16; ++i) {
    float xv = G[i * 256 + tid];
    vals[i] = xv;
    ss += xv * xv;
  }
#pragma unroll
  for (int off = 32; off; off >>= 1) ss += __shfl_xor(ss, off, 64);
  if (lane == 0) red[wv] = ss;
  __syncthreads();
  float tot = red[0] + red[1] + red[2] + red[3];
  float scale = 1.f / ((sqrtf(tot) + 1e-7f) * 1.01f);
#pragma unroll
  for (int i = 0; i < 16; ++i) {
    int idx = i * 256 + tid;
    int row = idx >> 6, col = idx & 63;
    _Float16 h, l;
    split_f16(vals[i] * scale, h, l);
    Xhi[row * BP + col] = h;  Xlo[row * BP + col] = l;
    XThi[col * BP + row] = h; XTlo[col * BP + row] = l;
  }

  const int mb = (wv >> 1) << 5;        // tile row base
  const int nb = (wv & 1) << 5;         // tile col base
  const int crow = ((lane >> 5) << 2);  // C-frag: + (r&3) + 8*(r>>2)
  const int ccol = lane & 31;

  for (int it = 0; it < 5; ++it) {
    const float ca = PE_A[it], cb = PE_B[it], cc = PE_C[it];
    __syncthreads();
    // ---- A = X X^T ----
    f32x16 accH, accL;
#pragma unroll
    for (int r = 0; r < 16; ++r) { accH[r] = 0.f; accL[r] = 0.f; }
#pragma unroll
    for (int ks = 0; ks < 4; ++ks) {
      half8 ah = ldfrag(Xhi, mb, ks, lane), al = ldfrag(Xlo, mb, ks, lane);
      half8 bh = ldfrag(Xhi, nb, ks, lane), bl = ldfrag(Xlo, nb, ks, lane);
      MFMA2(accH, accL, ah, al, bh, bl);
    }
    float Aval[16];
#pragma unroll
    for (int r = 0; r < 16; ++r) {
      Aval[r] = accH[r] + accL[r] * INV_S;
      int rr = mb + crow + (r & 3) + ((r >> 2) << 3);
      int cc2 = nb + ccol;
      _Float16 h, l;
      split_f16(Aval[r], h, l);
      Ahi[rr * BP + cc2] = h; Alo[rr * BP + cc2] = l;
    }
    __syncthreads();
    // ---- A2 = A A (A symmetric: B-op reads rows of A) ----
    f32x16 acc2H, acc2L;
#pragma unroll
    for (int r = 0; r < 16; ++r) { acc2H[r] = 0.f; acc2L[r] = 0.f; }
#pragma unroll
    for (int ks = 0; ks < 4; ++ks) {
      half8 ah = ldfrag(Ahi, mb, ks, lane), al = ldfrag(Alo, mb, ks, lane);
      half8 bh = ldfrag(Ahi, nb, ks, lane), bl = ldfrag(Alo, nb, ks, lane);
      MFMA2(acc2H, acc2L, ah, al, bh, bl);
    }
    __syncthreads();
    // ---- Bm' = b A + c A2 + a I  -> overwrite A planes ----
#pragma unroll
    for (int r = 0; r < 16; ++r) {
      int rr = mb + crow + (r & 3) + ((r >> 2) << 3);
      int cc2 = nb + ccol;
      float bm = cb * Aval[r] + cc * (acc2H[r] + acc2L[r] * INV_S);
      if (rr == cc2) bm += ca;
      _Float16 h, l;
      split_f16(bm, h, l);
      Ahi[rr * BP + cc2] = h; Alo[rr * BP + cc2] = l;
    }
    __syncthreads();
    // ---- X' = Bm' X  (B-op: X[k][n] = XT row n) ----
    f32x16 accXH, accXL;
#pragma unroll
    for (int r = 0; r < 16; ++r) { accXH[r] = 0.f; accXL[r] = 0.f; }
#pragma unroll
    for (int ks = 0; ks < 4; ++ks) {
      half8 ah = ldfrag(Ahi, mb, ks, lane), al = ldfrag(Alo, mb, ks, lane);
      half8 bh = ldfrag(XThi, nb, ks, lane), bl = ldfrag(XTlo, nb, ks, lane);
      MFMA2(accXH, accXL, ah, al, bh, bl);
    }
    if (it < 4) {
      __syncthreads();  // all waves done reading X/XT
#pragma unroll
      for (int r = 0; r < 16; ++r) {
        int rr = mb + crow + (r & 3) + ((r >> 2) << 3);
        int cc2 = nb + ccol;
        _Float16 h, l;
        split_f16(accXH[r] + accXL[r] * INV_S, h, l);
        Xhi[rr * BP + cc2] = h;  Xlo[rr * BP + cc2] = l;
        XThi[cc2 * BP + rr] = h; XTlo[cc2 * BP + rr] = l;
      }
    } else {
      // ---- final store (fp32) ----
#pragma unroll
      for (int r = 0; r < 16; ++r) {
        int rr = mb + crow + (r & 3) + ((r >> 2) << 3);
        int cc2 = nb + ccol;
        G[rr * 64 + cc2] = accXH[r] + accXL[r] * INV_S;
      }
    }
  }
}

// ---------------------------------------------------------------------------
// B4: memory scan + read
// ---------------------------------------------------------------------------
__global__ __launch_bounds__(256) void mem_scan_kernel(const float* __restrict__ chunkS,
                                                       const float* __restrict__ qp,
                                                       const float* __restrict__ galpha,
                                                       float* __restrict__ Mst,
                                                       float* __restrict__ ybuf, int ci) {
  __shared__ float ql[CSz * Dsz];
  __shared__ float al[CSz];
  const int blk = blockIdx.x;
  const int bh = blk >> 4, eb = blk & 15;
  const int b = bh >> 4, h = bh & 15;
  const int tid = threadIdx.x;
  const int w = tid >> 6, lane = tid & 63;
  const int v = eb * 4 + w, k = lane;
  for (int i = tid; i < CSz * Dsz; i += 256) {
    int t = i >> 6, kk = i & 63;
    ql[i] = qp[(((size_t)b * Tsz + ci * CSz + t) * Hsz + h) * Dsz + kk];
  }
  if (tid < CSz) al[tid] = galpha[((size_t)b * Tsz + ci * CSz + tid) * Hsz + h];
  __syncthreads();
  float m = Mst[(size_t)bh * 4096 + v * 64 + k];
  const float* Xo = chunkS + (size_t)bh * CSz * 4096;
  for (int t = 0; t < CSz; ++t) {
    m = al[t] * m + Xo[(size_t)t * 4096 + v * 64 + k];
    float p = m * ql[t * 64 + k];
#pragma unroll
    for (int off = 32; off; off >>= 1) p += __shfl_xor(p, off, 64);
    if (lane == 0) ybuf[(((size_t)b * Tsz + ci * CSz + t) * Hsz + h) * Dsz + v] = p;
  }
  Mst[(size_t)bh * 4096 + v * 64 + k] = m;
}

// ---------------------------------------------------------------------------
extern "C" void kernel_launch(void* const* d_in, const int* in_sizes, int n_in,
                              void* d_out, int out_size, void* d_ws, size_t ws_size,
                              hipStream_t stream) {
  (void)in_sizes; (void)n_in; (void)out_size; (void)ws_size;
  const float* x   = (const float*)d_in[0];
  const float* Wq  = (const float*)d_in[1];
  const float* Wk  = (const float*)d_in[2];
  const float* Wv  = (const float*)d_in[3];
  const float* Wo  = (const float*)d_in[4];
  const float* cqw = (const float*)d_in[5];
  const float* cqb = (const float*)d_in[6];
  const float* ckw = (const float*)d_in[7];
  const float* ckb = (const float*)d_in[8];
  const float* cvw = (const float*)d_in[9];
  const float* cvb = (const float*)d_in[10];
  const float* Wa  = (const float*)d_in[11];
  const float* We  = (const float*)d_in[12];
  const float* Wt  = (const float*)d_in[13];
  const float* Wg  = (const float*)d_in[14];
  float* out = (float*)d_out;

  float* p = (float*)d_ws;
  const size_t NBTC = (size_t)Bsz * Tsz * Csz;
  const size_t NBTH = (size_t)Bsz * Tsz * Hsz;
  const size_t NMAT = (size_t)Bsz * Hsz * Dsz * Dsz;
  float* qlin = p; p += NBTC;
  float* klin = p; p += NBTC;
  float* vlin = p; p += NBTC;
  float* qp   = p; p += NBTC;
  float* kp   = p; p += NBTC;
  float* vp   = p; p += NBTC;
  float* ga   = p; p += NBTH;
  float* ge   = p; p += NBTH;
  float* gt   = p; p += NBTH;
  float* gg   = p; p += NBTH;
  float* Mst  = p; p += NMAT;
  float* Sst  = p; p += NMAT;
  float* errb = p; p += (size_t)Bsz * Hsz * CSz * Dsz;
  float* chS  = p; p += (size_t)Bsz * Hsz * CSz * Dsz * Dsz;
  float* ybuf = p; p += NBTC;
  float* ynrm = p; p += NBTC;

  hipMemsetAsync(Mst, 0, NMAT * sizeof(float), stream);
  hipMemsetAsync(Sst, 0, NMAT * sizeof(float), stream);

  dim3 gg16(16, 16);
  gemm_nt<<<gg16, 256, 0, stream>>>(x, Wq, qlin, Bsz * Tsz, Csz, Csz);
  gemm_nt<<<gg16, 256, 0, stream>>>(x, Wk, klin, Bsz * Tsz, Csz, Csz);
  gemm_nt<<<gg16, 256, 0, stream>>>(x, Wv, vlin, Bsz * Tsz, Csz, Csz);
  gates_kernel<<<Bsz * Tsz, 64, 0, stream>>>(x, Wa, We, Wt, Wg, ga, ge, gt, gg);
  conv_kernel<<<Bsz * Tsz, 256, 0, stream>>>(qlin, cqw, cqb, qp, 1);
  conv_kernel<<<Bsz * Tsz, 256, 0, stream>>>(klin, ckw, ckb, kp, 1);
  conv_kernel<<<Bsz * Tsz, 256, 0, stream>>>(vlin, cvw, cvb, vp, 0);

  for (int ci = 0; ci < NCHUNK; ++ci) {
    pred_err_kernel<<<Bsz * Hsz, 256, 0, stream>>>(Mst, kp, vp, errb, ci);
    mom_scan_kernel<<<Bsz * Hsz * 16, 256, 0, stream>>>(errb, kp, ge, gt, gg, Sst, chS, ci);
    pe_mfma_kernel<<<Bsz * Hsz * CSz, 256, 0, stream>>>(chS);
    mem_scan_kernel<<<Bsz * Hsz * 16, 256, 0, stream>>>(chS, qp, ga, Mst, ybuf, ci);
  }

  rms_kernel<<<Bsz * Tsz, 256, 0, stream>>>(ybuf, ynrm);
  gemm_nt<<<gg16, 256, 0, stream>>>(ynrm, Wo, out, Bsz * Tsz, Csz, Csz);
}

// Round 4
// 1272.170 us; speedup vs baseline: 2.6269x; 1.1661x over previous
//
#include <hip/hip_runtime.h>

// Problem constants
constexpr int Bsz = 2, Tsz = 512, Csz = 1024, Hsz = 16, Dsz = 64, CSz = 64;
constexpr int NCHUNK = 8, OW = 8;
constexpr int BP = 72;    // LDS row pitch (f16): multiple of 8 keeps b128 16B-aligned

// Polar Express quintic coefficients (first NS_STEPS=5 rows)
__constant__ float PE_A[5] = {8.28721201814563f, 4.107059111542203f, 3.9486908534822946f,
                              3.3184196573706015f, 2.300652019954817f};
__constant__ float PE_B[5] = {-23.595886519098837f, -2.9478499167379106f, -2.908902115962949f,
                              -2.488488024314874f, -1.6689039845747493f};
__constant__ float PE_C[5] = {17.300387312530933f, 0.5448431082926601f, 0.5518191394370137f,
                              0.51004894012372f, 0.4188073119525673f};

typedef __attribute__((ext_vector_type(8))) _Float16 half8;
typedef __attribute__((ext_vector_type(4))) _Float16 half4;
typedef __attribute__((ext_vector_type(16))) float f32x16;

// ---------------------------------------------------------------------------
// Generic tiled GEMM:  O[m][n] = sum_k A[m][k] * W[n][k]   (i.e. A @ W.T)
// ---------------------------------------------------------------------------
__global__ __launch_bounds__(256) void gemm_nt(const float* __restrict__ A,
                                               const float* __restrict__ W,
                                               float* __restrict__ O,
                                               int M, int N, int K) {
  __shared__ float As[16][68];
  __shared__ float Ws[16][68];
  const int tid = threadIdx.x;
  const int m0 = blockIdx.x * 64, n0 = blockIdx.y * 64;
  const int tm = tid & 15, tn = tid >> 4;
  const int lr = tid >> 2, lk = (tid & 3) << 2;
  float acc[4][4] = {};
  for (int k0 = 0; k0 < K; k0 += 16) {
    float4 av = *(const float4*)(A + (size_t)(m0 + lr) * K + k0 + lk);
    float4 wv = *(const float4*)(W + (size_t)(n0 + lr) * K + k0 + lk);
    __syncthreads();
    As[lk + 0][lr] = av.x; As[lk + 1][lr] = av.y; As[lk + 2][lr] = av.z; As[lk + 3][lr] = av.w;
    Ws[lk + 0][lr] = wv.x; Ws[lk + 1][lr] = wv.y; Ws[lk + 2][lr] = wv.z; Ws[lk + 3][lr] = wv.w;
    __syncthreads();
#pragma unroll
    for (int k = 0; k < 16; ++k) {
      float4 a4 = *(const float4*)&As[k][tm << 2];
      float4 w4 = *(const float4*)&Ws[k][tn << 2];
      float a_[4] = {a4.x, a4.y, a4.z, a4.w};
      float w_[4] = {w4.x, w4.y, w4.z, w4.w};
#pragma unroll
      for (int i = 0; i < 4; ++i)
#pragma unroll
        for (int j = 0; j < 4; ++j) acc[i][j] += a_[i] * w_[j];
    }
  }
#pragma unroll
  for (int i = 0; i < 4; ++i) {
    float4 o = {acc[i][0], acc[i][1], acc[i][2], acc[i][3]};
    *(float4*)(O + (size_t)(m0 + (tm << 2) + i) * N + n0 + (tn << 2)) = o;
  }
}

// ---------------------------------------------------------------------------
// Gates
// ---------------------------------------------------------------------------
__global__ __launch_bounds__(64) void gates_kernel(const float* __restrict__ x,
                                                   const float* __restrict__ Wa,
                                                   const float* __restrict__ We,
                                                   const float* __restrict__ Wt,
                                                   const float* __restrict__ Wg,
                                                   float* __restrict__ ga, float* __restrict__ ge,
                                                   float* __restrict__ gt, float* __restrict__ gg) {
  __shared__ float xs[Csz];
  const int bt = blockIdx.x;
  const int tid = threadIdx.x;
  const float* xr = x + (size_t)bt * Csz;
  for (int i = tid * 4; i < Csz; i += 64 * 4) *(float4*)&xs[i] = *(const float4*)&xr[i];
  __syncthreads();
  const int gsel = tid >> 4, h = tid & 15;
  const float* Wrow = (gsel == 0 ? Wa : gsel == 1 ? We : gsel == 2 ? Wt : Wg) + (size_t)h * Csz;
  float acc = 0.f;
  for (int i = 0; i < Csz; i += 4) {
    float4 w4 = *(const float4*)&Wrow[i];
    acc += xs[i] * w4.x + xs[i + 1] * w4.y + xs[i + 2] * w4.z + xs[i + 3] * w4.w;
  }
  float s = 1.f / (1.f + expf(-acc));
  float* outp = (gsel == 0 ? ga : gsel == 1 ? ge : gsel == 2 ? gt : gg);
  outp[(size_t)bt * Hsz + h] = s;
}

// ---------------------------------------------------------------------------
// Causal depthwise conv (K=4) + optional rms_norm/poly
// ---------------------------------------------------------------------------
__global__ __launch_bounds__(256) void conv_kernel(const float* __restrict__ lin,
                                                   const float* __restrict__ w,
                                                   const float* __restrict__ bias,
                                                   float* __restrict__ out, int do_norm) {
  const int bt = blockIdx.x;
  const int b = bt >> 9, t = bt & 511;
  const int tid = threadIdx.x;
  const int c0 = tid << 2;
  float4 bv = *(const float4*)&bias[c0];
  float v0 = bv.x, v1 = bv.y, v2 = bv.z, v3 = bv.w;
  float4 w0 = *(const float4*)&w[(c0 + 0) * 4];
  float4 w1 = *(const float4*)&w[(c0 + 1) * 4];
  float4 w2 = *(const float4*)&w[(c0 + 2) * 4];
  float4 w3 = *(const float4*)&w[(c0 + 3) * 4];
  const float* base = lin + (size_t)b * Tsz * Csz + c0;
#pragma unroll
  for (int j = 0; j < 4; ++j) {
    int tt = t - 3 + j;
    if (tt < 0) continue;
    float4 xv = *(const float4*)(base + (size_t)tt * Csz);
    v0 += xv.x * (&w0.x)[j];
    v1 += xv.y * (&w1.x)[j];
    v2 += xv.z * (&w2.x)[j];
    v3 += xv.w * (&w3.x)[j];
  }
  if (do_norm) {
    float ss = v0 * v0 + v1 * v1 + v2 * v2 + v3 * v3;
    ss += __shfl_xor(ss, 1, 16);
    ss += __shfl_xor(ss, 2, 16);
    ss += __shfl_xor(ss, 4, 16);
    ss += __shfl_xor(ss, 8, 16);
    float scl = rsqrtf(ss * (1.f / 64.f) + 1e-6f);
    v0 *= scl; v1 *= scl; v2 *= scl; v3 *= scl;
    v0 += 0.5f * v0 * v0; v1 += 0.5f * v1 * v1; v2 += 0.5f * v2 * v2; v3 += 0.5f * v3 * v3;
  }
  float4 o = {v0, v1, v2, v3};
  *(float4*)(out + (size_t)bt * Csz + c0) = o;
}

// ---------------------------------------------------------------------------
// rms_norm for y
// ---------------------------------------------------------------------------
__global__ __launch_bounds__(256) void rms_kernel(const float* __restrict__ in,
                                                  float* __restrict__ out) {
  const int bt = blockIdx.x;
  const int tid = threadIdx.x;
  const int c0 = tid << 2;
  float4 xv = *(const float4*)(in + (size_t)bt * Csz + c0);
  float ss = xv.x * xv.x + xv.y * xv.y + xv.z * xv.z + xv.w * xv.w;
  ss += __shfl_xor(ss, 1, 16);
  ss += __shfl_xor(ss, 2, 16);
  ss += __shfl_xor(ss, 4, 16);
  ss += __shfl_xor(ss, 8, 16);
  float scl = rsqrtf(ss * (1.f / 64.f) + 1e-6f);
  float4 o = {xv.x * scl, xv.y * scl, xv.z * scl, xv.w * scl};
  *(float4*)(out + (size_t)bt * Csz + c0) = o;
}

// ---------------------------------------------------------------------------
// B1+B2 fused: err = M k - v  (for this block's 4 v-rows), then
// omega window + momentum scan. Thread per (v,k) element of S.
// Grid: (B*H)*16 blocks; block eb handles v-rows eb*4..eb*4+3.
// ---------------------------------------------------------------------------
__global__ __launch_bounds__(256) void mom_scan_kernel(const float* __restrict__ Mst,
                                                       const float* __restrict__ kp,
                                                       const float* __restrict__ vp,
                                                       const float* __restrict__ geta,
                                                       const float* __restrict__ gtheta,
                                                       const float* __restrict__ ggamma,
                                                       float* __restrict__ Sst,
                                                       float* __restrict__ chunkS, int ci) {
  __shared__ float Ml[4 * Dsz];     // 4 M-rows of this block
  __shared__ float errl[256];       // [t][vloc]
  __shared__ float kkl[CSz * Dsz];  // [t][k]
  __shared__ float gl[CSz], el[CSz], tl[CSz];
  const int blk = blockIdx.x;
  const int bh = blk >> 4, eb = blk & 15;
  const int b = bh >> 4, h = bh & 15;
  const int tid = threadIdx.x;
  // stage loads
  Ml[tid & 255] = Mst[(size_t)bh * 4096 + eb * 4 * 64 + tid];  // [vl][k], vl=tid>>6
#pragma unroll
  for (int i = 0; i < 16; ++i) {
    int idx = i * 256 + tid;
    int t = idx >> 6, k = idx & 63;
    kkl[idx] = kp[(((size_t)b * Tsz + ci * CSz + t) * Hsz + h) * Dsz + k];
  }
  if (tid < CSz) {
    size_t gi = ((size_t)b * Tsz + ci * CSz + tid) * Hsz + h;
    gl[tid] = ggamma[gi];
    el[tid] = geta[gi];
    tl[tid] = gtheta[gi];
  }
  __syncthreads();
  // err[t][vl] = dot(M[eb*4+vl], k[t]) - v_c[t][eb*4+vl]
  {
    const int tt = tid >> 2, vl = tid & 3;
    float acc = 0.f;
#pragma unroll 8
    for (int k = 0; k < Dsz; ++k) acc += Ml[vl * 64 + k] * kkl[tt * 64 + k];
    float vv = vp[(((size_t)b * Tsz + ci * CSz + tt) * Hsz + h) * Dsz + eb * 4 + vl];
    errl[tt * 4 + vl] = acc - vv;
  }
  __syncthreads();
  const int e = eb * 256 + tid;
  const int vloc = tid >> 6;
  const int k = tid & 63;
  float S = Sst[(size_t)bh * 4096 + e];
  float ring[OW];
  float wsum = 0.f;
  float* outp = chunkS + (size_t)bh * CSz * 4096 + e;
#pragma unroll
  for (int t = 0; t < CSz; ++t) {
    float u = 2.f * errl[t * 4 + vloc] * kkl[t * 64 + k];
    float val = gl[t] * u;
    wsum += val;
    if (t >= OW) wsum -= ring[t & (OW - 1)];
    ring[t & (OW - 1)] = val;
    S = tl[t] * S - el[t] * wsum;
    outp[(size_t)t * 4096] = S;
  }
  Sst[(size_t)bh * 4096 + e] = S;
}

// ---------------------------------------------------------------------------
// B3: Polar Express via scaled split-f16 MFMA.
// One 256-thread block (4 waves) per 64x64 matrix; each wave owns one 32x32
// output tile. All MFMA operand reads are contiguous LDS rows; symmetric
// outputs (A, Bm) and the XT plane are written TRANSPOSED so the C-fragment's
// 4-consecutive-row groups become contiguous ds_write_b64s.
//   A  = X X^T        : A-op rows of X, B-op rows of X
//   A2 = A A          : A symmetric -> B-op rows of A
//   X' = (aI+bA+cA2) X: A-op rows of Bm (symmetric), B-op rows of XT
// fp32 v ~= hi + (lo/2048); products hh -> accH, h*lo + lo*h -> accL.
// ---------------------------------------------------------------------------
__device__ __forceinline__ void split_f16(float v, _Float16& hi, _Float16& lo) {
  _Float16 h = (_Float16)v;                 // RN
  float r = v - (float)h;                   // exact residual
  hi = h;
  lo = (_Float16)(r * 2048.0f);             // RN, scaled into normal range
}

__device__ __forceinline__ half8 ldfrag(const _Float16* P, int rowbase, int ks, int lane) {
  // fragment for v_mfma_f32_32x32x16_f16: lane -> m/n = lane&31, k = 8*(lane>>5)+j
  int row = rowbase + (lane & 31);
  int col = (ks << 4) + ((lane >> 5) << 3);
  return *(const half8*)&P[row * BP + col];
}

#define MFMA2(accH, accL, ah, al, bh, bl)                                     \
  accH = __builtin_amdgcn_mfma_f32_32x32x16_f16(ah, bh, accH, 0, 0, 0);       \
  accL = __builtin_amdgcn_mfma_f32_32x32x16_f16(ah, bl, accL, 0, 0, 0);       \
  accL = __builtin_amdgcn_mfma_f32_32x32x16_f16(al, bh, accL, 0, 0, 0);

// Write this wave's 16 C-values transposed into a (symmetric or transpose-
// target) plane pair as 4+4 ds_write_b64: row = nb+ccol, cols mb+crow+8g+j.
__device__ __forceinline__ void store_sym_t(_Float16* Phi, _Float16* Plo,
                                            const float* vals16, int mb, int nb,
                                            int crow, int ccol) {
#pragma unroll
  for (int g = 0; g < 4; ++g) {
    half4 hv, lv;
#pragma unroll
    for (int j = 0; j < 4; ++j) {
      _Float16 h, l;
      split_f16(vals16[g * 4 + j], h, l);
      hv[j] = h; lv[j] = l;
    }
    int off = (nb + ccol) * BP + mb + crow + 8 * g;
    *(half4*)&Phi[off] = hv;
    *(half4*)&Plo[off] = lv;
  }
}

__global__ __launch_bounds__(256) void pe_mfma_kernel(float* __restrict__ chunkS) {
  __shared__ __attribute__((aligned(16))) _Float16 Xhi[64 * BP];
  __shared__ __attribute__((aligned(16))) _Float16 Xlo[64 * BP];
  __shared__ __attribute__((aligned(16))) _Float16 XThi[64 * BP];
  __shared__ __attribute__((aligned(16))) _Float16 XTlo[64 * BP];
  __shared__ __attribute__((aligned(16))) _Float16 Ahi[64 * BP];
  __shared__ __attribute__((aligned(16))) _Float16 Alo[64 * BP];
  __shared__ __attribute__((aligned(16))) _Float16 Bhi[64 * BP];
  __shared__ __attribute__((aligned(16))) _Float16 Blo[64 * BP];
  __shared__ float red[4];
  const int tid = threadIdx.x;
  const int lane = tid & 63;
  const int wv = tid >> 6;
  float* G = chunkS + (size_t)blockIdx.x * 4096;
  constexpr float INV_S = 1.0f / 2048.0f;

  // ---- load + Frobenius normalize ----
  float vals[16];
  float ss = 0.f;
#pragma unroll
  for (int i = 0; i < 16; ++i) {
    float xv = G[i * 256 + tid];
    vals[i] = xv;
    ss += xv * xv;
  }
#pragma unroll
  for (int off = 32; off; off >>= 1) ss += __shfl_xor(ss, off, 64);
  if (lane == 0) red[wv] = ss;
  __syncthreads();
  float tot = red[0] + red[1] + red[2] + red[3];
  float scale = 1.f / ((sqrtf(tot) + 1e-7f) * 1.01f);
#pragma unroll
  for (int i = 0; i < 16; ++i) {
    int idx = i * 256 + tid;
    int row = idx >> 6, col = idx & 63;
    _Float16 h, l;
    split_f16(vals[i] * scale, h, l);
    Xhi[row * BP + col] = h;  Xlo[row * BP + col] = l;
    XThi[col * BP + row] = h; XTlo[col * BP + row] = l;
  }

  const int mb = (wv >> 1) << 5;        // tile row base
  const int nb = (wv & 1) << 5;         // tile col base
  const int crow = ((lane >> 5) << 2);  // C-frag: row = mb+crow+(r&3)+8*(r>>2)
  const int ccol = lane & 31;           // C-frag: col = nb+ccol

  for (int it = 0; it < 5; ++it) {
    const float ca = PE_A[it], cb = PE_B[it], cc = PE_C[it];
    __syncthreads();  // B1: X/XT ready
    // ---- A = X X^T ----
    f32x16 accH, accL;
#pragma unroll
    for (int r = 0; r < 16; ++r) { accH[r] = 0.f; accL[r] = 0.f; }
#pragma unroll
    for (int ks = 0; ks < 4; ++ks) {
      half8 ah = ldfrag(Xhi, mb, ks, lane), al = ldfrag(Xlo, mb, ks, lane);
      half8 bh = ldfrag(Xhi, nb, ks, lane), bl = ldfrag(Xlo, nb, ks, lane);
      MFMA2(accH, accL, ah, al, bh, bl);
    }
    float Aval[16];
#pragma unroll
    for (int r = 0; r < 16; ++r) Aval[r] = accH[r] + accL[r] * INV_S;
    store_sym_t(Ahi, Alo, Aval, mb, nb, crow, ccol);  // A symmetric: b64 writes
    __syncthreads();  // B2: A complete
    // ---- A2 = A A (A symmetric: B-op reads rows of A) ----
    f32x16 acc2H, acc2L;
#pragma unroll
    for (int r = 0; r < 16; ++r) { acc2H[r] = 0.f; acc2L[r] = 0.f; }
#pragma unroll
    for (int ks = 0; ks < 4; ++ks) {
      half8 ah = ldfrag(Ahi, mb, ks, lane), al = ldfrag(Alo, mb, ks, lane);
      half8 bh = ldfrag(Ahi, nb, ks, lane), bl = ldfrag(Alo, nb, ks, lane);
      MFMA2(acc2H, acc2L, ah, al, bh, bl);
    }
    // ---- Bm = b A + c A2 + a I  -> separate B planes (no WAR on A) ----
    float Bval[16];
#pragma unroll
    for (int r = 0; r < 16; ++r) {
      int rr = mb + crow + (r & 3) + ((r >> 2) << 3);
      int cc2 = nb + ccol;
      float bm = cb * Aval[r] + cc * (acc2H[r] + acc2L[r] * INV_S);
      if (rr == cc2) bm += ca;
      Bval[r] = bm;
    }
    store_sym_t(Bhi, Blo, Bval, mb, nb, crow, ccol);  // Bm symmetric: b64 writes
    __syncthreads();  // B3: Bm complete
    // ---- X' = Bm X  (B-op: X[k][n] = XT row n) ----
    f32x16 accXH, accXL;
#pragma unroll
    for (int r = 0; r < 16; ++r) { accXH[r] = 0.f; accXL[r] = 0.f; }
#pragma unroll
    for (int ks = 0; ks < 4; ++ks) {
      half8 ah = ldfrag(Bhi, mb, ks, lane), al = ldfrag(Blo, mb, ks, lane);
      half8 bh = ldfrag(XThi, nb, ks, lane), bl = ldfrag(XTlo, nb, ks, lane);
      MFMA2(accXH, accXL, ah, al, bh, bl);
    }
    if (it < 4) {
      __syncthreads();  // B4: all stage-3 reads of X/XT done
      float Xval[16];
#pragma unroll
      for (int r = 0; r < 16; ++r) Xval[r] = accXH[r] + accXL[r] * INV_S;
      // XT plane: transposed -> contiguous b64 writes
      store_sym_t(XThi, XTlo, Xval, mb, nb, crow, ccol);
      // X plane: column-fragment b16 writes (unavoidable)
#pragma unroll
      for (int r = 0; r < 16; ++r) {
        int rr = mb + crow + (r & 3) + ((r >> 2) << 3);
        int cc2 = nb + ccol;
        _Float16 h, l;
        split_f16(Xval[r], h, l);
        Xhi[rr * BP + cc2] = h;  Xlo[rr * BP + cc2] = l;
      }
    } else {
      // ---- final store (fp32) ----
#pragma unroll
      for (int r = 0; r < 16; ++r) {
        int rr = mb + crow + (r & 3) + ((r >> 2) << 3);
        int cc2 = nb + ccol;
        G[rr * 64 + cc2] = accXH[r] + accXL[r] * INV_S;
      }
    }
  }
}

// ---------------------------------------------------------------------------
// B4: memory scan + read
// ---------------------------------------------------------------------------
__global__ __launch_bounds__(256) void mem_scan_kernel(const float* __restrict__ chunkS,
                                                       const float* __restrict__ qp,
                                                       const float* __restrict__ galpha,
                                                       float* __restrict__ Mst,
                                                       float* __restrict__ ybuf, int ci) {
  __shared__ float ql[CSz * Dsz];
  __shared__ float al[CSz];
  const int blk = blockIdx.x;
  const int bh = blk >> 4, eb = blk & 15;
  const int b = bh >> 4, h = bh & 15;
  const int tid = threadIdx.x;
  const int w = tid >> 6, lane = tid & 63;
  const int v = eb * 4 + w, k = lane;
  for (int i = tid; i < CSz * Dsz; i += 256) {
    int t = i >> 6, kk = i & 63;
    ql[i] = qp[(((size_t)b * Tsz + ci * CSz + t) * Hsz + h) * Dsz + kk];
  }
  if (tid < CSz) al[tid] = galpha[((size_t)b * Tsz + ci * CSz + tid) * Hsz + h];
  __syncthreads();
  float m = Mst[(size_t)bh * 4096 + v * 64 + k];
  const float* Xo = chunkS + (size_t)bh * CSz * 4096;
  for (int t = 0; t < CSz; ++t) {
    m = al[t] * m + Xo[(size_t)t * 4096 + v * 64 + k];
    float p = m * ql[t * 64 + k];
#pragma unroll
    for (int off = 32; off; off >>= 1) p += __shfl_xor(p, off, 64);
    if (lane == 0) ybuf[(((size_t)b * Tsz + ci * CSz + t) * Hsz + h) * Dsz + v] = p;
  }
  Mst[(size_t)bh * 4096 + v * 64 + k] = m;
}

// ---------------------------------------------------------------------------
extern "C" void kernel_launch(void* const* d_in, const int* in_sizes, int n_in,
                              void* d_out, int out_size, void* d_ws, size_t ws_size,
                              hipStream_t stream) {
  (void)in_sizes; (void)n_in; (void)out_size; (void)ws_size;
  const float* x   = (const float*)d_in[0];
  const float* Wq  = (const float*)d_in[1];
  const float* Wk  = (const float*)d_in[2];
  const float* Wv  = (const float*)d_in[3];
  const float* Wo  = (const float*)d_in[4];
  const float* cqw = (const float*)d_in[5];
  const float* cqb = (const float*)d_in[6];
  const float* ckw = (const float*)d_in[7];
  const float* ckb = (const float*)d_in[8];
  const float* cvw = (const float*)d_in[9];
  const float* cvb = (const float*)d_in[10];
  const float* Wa  = (const float*)d_in[11];
  const float* We  = (const float*)d_in[12];
  const float* Wt  = (const float*)d_in[13];
  const float* Wg  = (const float*)d_in[14];
  float* out = (float*)d_out;

  float* p = (float*)d_ws;
  const size_t NBTC = (size_t)Bsz * Tsz * Csz;
  const size_t NBTH = (size_t)Bsz * Tsz * Hsz;
  const size_t NMAT = (size_t)Bsz * Hsz * Dsz * Dsz;
  float* qlin = p; p += NBTC;
  float* klin = p; p += NBTC;
  float* vlin = p; p += NBTC;
  float* qp   = p; p += NBTC;
  float* kp   = p; p += NBTC;
  float* vp   = p; p += NBTC;
  float* ga   = p; p += NBTH;
  float* ge   = p; p += NBTH;
  float* gt   = p; p += NBTH;
  float* gg   = p; p += NBTH;
  float* Mst  = p; p += NMAT;
  float* Sst  = p; p += NMAT;
  float* chS  = p; p += (size_t)Bsz * Hsz * CSz * Dsz * Dsz;
  float* ybuf = p; p += NBTC;
  float* ynrm = p; p += NBTC;

  hipMemsetAsync(Mst, 0, NMAT * sizeof(float), stream);
  hipMemsetAsync(Sst, 0, NMAT * sizeof(float), stream);

  dim3 gg16(16, 16);
  gemm_nt<<<gg16, 256, 0, stream>>>(x, Wq, qlin, Bsz * Tsz, Csz, Csz);
  gemm_nt<<<gg16, 256, 0, stream>>>(x, Wk, klin, Bsz * Tsz, Csz, Csz);
  gemm_nt<<<gg16, 256, 0, stream>>>(x, Wv, vlin, Bsz * Tsz, Csz, Csz);
  gates_kernel<<<Bsz * Tsz, 64, 0, stream>>>(x, Wa, We, Wt, Wg, ga, ge, gt, gg);
  conv_kernel<<<Bsz * Tsz, 256, 0, stream>>>(qlin, cqw, cqb, qp, 1);
  conv_kernel<<<Bsz * Tsz, 256, 0, stream>>>(klin, ckw, ckb, kp, 1);
  conv_kernel<<<Bsz * Tsz, 256, 0, stream>>>(vlin, cvw, cvb, vp, 0);

  for (int ci = 0; ci < NCHUNK; ++ci) {
    mom_scan_kernel<<<Bsz * Hsz * 16, 256, 0, stream>>>(Mst, kp, vp, ge, gt, gg, Sst, chS, ci);
    pe_mfma_kernel<<<Bsz * Hsz * CSz, 256, 0, stream>>>(chS);
    mem_scan_kernel<<<Bsz * Hsz * 16, 256, 0, stream>>>(chS, qp, ga, Mst, ybuf, ci);
  }

  rms_kernel<<<Bsz * Tsz, 256, 0, stream>>>(ybuf, ynrm);
  gemm_nt<<<gg16, 256, 0, stream>>>(ynrm, Wo, out, Bsz * Tsz, Csz, Csz);
}